// Round 8
// baseline (293.322 us; speedup 1.0000x reference)
//
#include <hip/hip_runtime.h>
#include <hip/hip_fp16.h>
#include <math.h>

// LinearCaps2d, BATCH=256, N = B_TYPES*H*W = 2048, C=10, POSE=16, 3 routing iters.
// R8: occupancy push. One-time f32->f16 prep for weight/poses (staging loses all cvt VALU).
//   pass_k: 512-thr blocks = 8 waves = 4 b-tiles x 2 n-halves; 2 iters of 8-n staging;
//   n-half partials combined in LDS before atomic flush (atomic count unchanged vs R7).
//   Phase A transposed MFMA 16x16x16 + fdot2 + 2 shfl (verified R7); phase B K=32 (verified R3).
// ws: s0,s1,s2 [40960] f32; w16 [5242880] f16; x16 [8388608] f16  (~27.8 MB).

typedef _Float16 f16;
typedef _Float16 f16x2 __attribute__((ext_vector_type(2)));
typedef _Float16 f16x4 __attribute__((ext_vector_type(4)));
typedef _Float16 f16x8 __attribute__((ext_vector_type(8)));
typedef __fp16   h16x2 __attribute__((ext_vector_type(2)));
typedef float f32x4 __attribute__((ext_vector_type(4)));

__device__ __forceinline__ f16x2 pk(float a, float b) {
    h16x2 t = __builtin_amdgcn_cvt_pkrtz(a, b);
    return __builtin_bit_cast(f16x2, t);
}

#if __has_builtin(__builtin_amdgcn_fdot2)
__device__ __forceinline__ float FDOT2(f16x2 a, f16x2 b, float c) {
    return __builtin_amdgcn_fdot2(__builtin_bit_cast(h16x2, a),
                                  __builtin_bit_cast(h16x2, b), c, false);
}
#else
__device__ __forceinline__ float FDOT2(f16x2 a, f16x2 b, float c) {
    return c + (float)a[0] * (float)b[0] + (float)a[1] * (float)b[1];
}
#endif

constexpr int WS_ROW = 24;    // f16 row stride (16 i + 8 pad) = 48 B, 16B-aligned
constexpr int XS_ROW = 136;   // f16 row stride (8n x 16 i + 8 pad) = 272 B, 16B-aligned

__device__ __forceinline__ float xorsum4(float v) {
    v += __shfl_xor(v, 16, 64);
    v += __shfl_xor(v, 32, 64);
    return v;
}

// ---- one-time f32 -> f16 conversion; one 8-float pair per thread
__global__ __launch_bounds__(256)
void prep_k(const float* __restrict__ src, f16* __restrict__ dst, int npair)
{
    const int i = blockIdx.x * 256 + threadIdx.x;
    if (i >= npair) return;
    float4 a = ((const float4*)src)[2 * i];
    float4 b = ((const float4*)src)[2 * i + 1];
    f16x2 p0 = pk(a.x, a.y), p1 = pk(a.z, a.w), p2 = pk(b.x, b.y), p3 = pk(b.z, b.w);
    f16x8 r;
    r[0] = p0[0]; r[1] = p0[1]; r[2] = p1[0]; r[3] = p1[1];
    r[4] = p2[0]; r[5] = p2[1]; r[6] = p3[0]; r[7] = p3[1];
    *(f16x8*)&dst[(size_t)i * 8] = r;
}

// grid: 512 blocks = 128 n-groups (16 n) x 4 b-groups (64 b); 512 thr = 8 waves.
// wave = (b-tile t in 0..3, n-half h in 0..1); each wave: 2 iters x 4 n.
template<int PASS>
__global__ __launch_bounds__(512, 4)
void pass_k(const f16* __restrict__ x16, const f16* __restrict__ w16,
            const float* __restrict__ bias,
            const float* __restrict__ sp0, const float* __restrict__ sp1,
            float* __restrict__ s_dst)
{
    __shared__ f16 Ws[1280 * WS_ROW];   // 8n x 160 rows -> 61440 B
    __shared__ f16 xs[64 * XS_ROW];     // 17408 B   (total 78848 B -> 2 blocks/CU)

    const int tid  = threadIdx.x;
    const int blk  = blockIdx.x;
    const int ngrp = blk >> 2;            // 128 n-groups (16 n each)
    const int b0   = (blk & 3) * 64;      // 4 b-groups
    const int wave = tid >> 6;
    const int lane = tid & 63;
    const int q    = lane >> 4;
    const int lo   = lane & 15;
    const int t    = wave & 3;            // b-tile
    const int h    = wave >> 2;           // n-half
    const int wtb  = t * 16;
    const int bg   = b0 + wtb;
    const int hbase = h * 4;              // n offset within the staged 8-n tile
    const int nl0  = q >> 1;
    const int iq   = (q & 1) * 8;

    // ---- inline squash: vsum fragment (b = bg+lo, o = q*4..q*4+3), packed f16
    f16x2 vsp[10][2];
    if (PASS >= 1) {
        const int rowb = (bg + lo) * 10;
        #pragma unroll
        for (int c = 0; c < 10; ++c) {
            float4 bb = *(const float4*)(bias + c * 16 + q * 4);
            float4 sa = *(const float4*)(sp0 + (size_t)(rowb + c) * 16 + q * 4);
            float t0 = sa.x + bb.x, t1 = sa.y + bb.y, t2 = sa.z + bb.z, t3 = sa.w + bb.w;
            float n2 = xorsum4(t0*t0 + t1*t1 + t2*t2 + t3*t3);
            float sc = n2 / (1.f + n2) * rsqrtf(n2 + 1e-8f);
            float v0 = sc*t0, v1 = sc*t1, v2 = sc*t2, v3 = sc*t3;
            if (PASS == 2) {
                float4 sb = *(const float4*)(sp1 + (size_t)(rowb + c) * 16 + q * 4);
                float u0 = sb.x + bb.x, u1 = sb.y + bb.y, u2 = sb.z + bb.z, u3 = sb.w + bb.w;
                float m2 = xorsum4(u0*u0 + u1*u1 + u2*u2 + u3*u3);
                float sc2 = m2 / (1.f + m2) * rsqrtf(m2 + 1e-8f);
                v0 += sc2*u0; v1 += sc2*u1; v2 += sc2*u2; v3 += sc2*u3;
            }
            vsp[c][0] = pk(v0, v1);
            vsp[c][1] = pk(v2, v3);
        }
    }

    // ---- staging: per iter 8 n (20480 f16 W, 8192 f16 x), pure f16 moves
    f16x8 wreg[5];
    f16x8 xreg[2];
    const int b_loc = tid >> 3, part = tid & 7;

    auto load_iter = [&](int l) {
        const f16* wp = w16 + (size_t)(ngrp * 16 + l * 8) * 2560;
        #pragma unroll
        for (int k = 0; k < 5; ++k)
            wreg[k] = ((const f16x8*)wp)[tid + k * 512];
        const f16* xp = x16 + (size_t)(b0 + b_loc) * 32768
                        + (size_t)(ngrp * 16 + l * 8 + part) * 16;
        xreg[0] = ((const f16x8*)xp)[0];
        xreg[1] = ((const f16x8*)xp)[1];
    };
    auto store_iter = [&]() {
        #pragma unroll
        for (int k = 0; k < 5; ++k) {
            const int f = tid + k * 512;          // f16x8 index in [0,2560)
            *(f16x8*)&Ws[(f >> 1) * WS_ROW + (f & 1) * 8] = wreg[k];
        }
        f16* lp = xs + b_loc * XS_ROW + part * 16;
        *(f16x8*)&lp[0] = xreg[0];
        *(f16x8*)&lp[8] = xreg[1];
    };

    f32x4 acc[10];
    #pragma unroll
    for (int c = 0; c < 10; ++c) acc[c] = (f32x4){0.f, 0.f, 0.f, 0.f};

    f16x2 cf[10][2];

    load_iter(0);

    for (int l = 0; l < 2; ++l) {
        __syncthreads();
        store_iter();
        if (l == 0) load_iter(1);
        __syncthreads();

        if (PASS >= 1) {
            // ---- phase A: votes^T via 16x16x16 MFMA (D[o][b]); logits = fdot2 + 2 shfl
            float ce[10];
            #pragma unroll
            for (int n = 0; n < 4; ++n) {
                const int n8 = hbase + n;
                f16x4 bx = *(const f16x4*)&xs[(wtb + lo) * XS_ROW + n8 * 16 + q * 4];
                float lg[10];
                #pragma unroll
                for (int c = 0; c < 10; ++c) {
                    f16x4 aw = *(const f16x4*)&Ws[((n8 * 10 + c) * 16 + lo) * WS_ROW + q * 4];
                    f32x4 D = __builtin_amdgcn_mfma_f32_16x16x16f16(
                        aw, bx, (f32x4){0.f, 0.f, 0.f, 0.f}, 0, 0, 0);
                    float p = FDOT2(pk(D[0], D[1]), vsp[c][0], 0.f);
                    p = FDOT2(pk(D[2], D[3]), vsp[c][1], p);
                    lg[c] = xorsum4(p);
                }
                float m = lg[0];
                #pragma unroll
                for (int c = 1; c < 10; ++c) m = fmaxf(m, lg[c]);
                float sum = 0.f;
                #pragma unroll
                for (int c = 0; c < 10; ++c) { lg[c] = __expf(lg[c] - m); sum += lg[c]; }
                const float inv = 1.f / sum;
                if (n & 1) {
                    #pragma unroll
                    for (int c = 0; c < 10; ++c) cf[c][n >> 1] = pk(ce[c], lg[c] * inv);
                } else {
                    #pragma unroll
                    for (int c = 0; c < 10; ++c) ce[c] = lg[c] * inv;
                }
            }
        }

        // ---- phase B: acc += (coeff*x) W  (K=32 = 2 n x 16 i), all LDS reads b128
        f16x8 xa[2];
        #pragma unroll
        for (int np = 0; np < 2; ++np)
            xa[np] = *(const f16x8*)&xs[(wtb + lo) * XS_ROW + (hbase + np * 2 + nl0) * 16 + iq];
        #pragma unroll
        for (int c = 0; c < 10; ++c) {
            #pragma unroll
            for (int np = 0; np < 2; ++np) {
                f16 ch;
                if (PASS == 0) {
                    ch = (f16)0.1f;
                } else {
                    union { f16x2 h2; unsigned u; } cu; cu.h2 = cf[c][np];
                    unsigned hv = nl0 ? (cu.u >> 16) : (cu.u & 0xffffu);
                    union { unsigned short s; f16 hh; } hu; hu.s = (unsigned short)hv;
                    ch = hu.hh;
                }
                const int n8 = hbase + np * 2 + nl0;
                f16x8 bw = *(const f16x8*)&Ws[((n8 * 10 + c) * 16 + lo) * WS_ROW + iq];
                f16x8 av = xa[np] * ch;
                acc[c] = __builtin_amdgcn_mfma_f32_16x16x32_f16(av, bw, acc[c], 0, 0, 0);
            }
        }
    }

    // ---- combine n-halves in LDS (padded stride 17 breaks q-group bank aliasing)
    __syncthreads();
    float* xch = (float*)Ws;   // 43512 B used <= 61440 B
    if (h == 1) {
        #pragma unroll
        for (int c = 0; c < 10; ++c)
            #pragma unroll
            for (int r = 0; r < 4; ++r)
                xch[((t * 16 + q * 4 + r) * 10 + c) * 17 + lo] = acc[c][r];
    }
    __syncthreads();
    if (h == 0) {
        #pragma unroll
        for (int c = 0; c < 10; ++c) {
            #pragma unroll
            for (int r = 0; r < 4; ++r) {
                float val = acc[c][r] + xch[((t * 16 + q * 4 + r) * 10 + c) * 17 + lo];
                unsafeAtomicAdd(s_dst + ((size_t)(bg + q * 4 + r) * 10 + c) * 16 + lo, val);
            }
        }
    }
}

// final squash: 2560 rows, one (b,c) per thread (verified R3/R7).
__global__ __launch_bounds__(256)
void epi_k(const float* __restrict__ s2, const float* __restrict__ bias,
           float* __restrict__ out)
{
    const int t = blockIdx.x * 256 + threadIdx.x;
    if (t >= 2560) return;
    const int c = t % 10;
    const float* sp = s2 + (size_t)t * 16;
    const float* bp = bias + c * 16;
    float sv[16];
    float n2 = 0.f;
    #pragma unroll
    for (int o = 0; o < 16; ++o) { float v = sp[o] + bp[o]; sv[o] = v; n2 += v * v; }
    const float scale = n2 / (1.f + n2) * rsqrtf(n2 + 1e-8f);
    float a2 = 0.f;
    #pragma unroll
    for (int o = 0; o < 16; ++o) {
        float v = scale * sv[o];
        out[(size_t)t * 16 + o] = v;
        a2 += v * v;
    }
    out[40960 + t] = sqrtf(a2 + 1e-8f);
}

extern "C" void kernel_launch(void* const* d_in, const int* in_sizes, int n_in,
                              void* d_out, int out_size, void* d_ws, size_t ws_size,
                              hipStream_t stream)
{
    const float* poses  = (const float*)d_in[0];
    // d_in[1] (input_caps_activations) unused by the reference.
    const float* weight = (const float*)d_in[2];
    const float* bias   = (const float*)d_in[3];
    float* out = (float*)d_out;

    float* s0 = (float*)d_ws;
    float* s1 = s0 + 40960;
    float* s2 = s1 + 40960;
    f16*   w16 = (f16*)(s2 + 40960);           // 5242880 f16
    f16*   x16 = w16 + 5242880;                // 8388608 f16

    (void)hipMemsetAsync(d_ws, 0, 3 * 40960 * sizeof(float), stream);

    prep_k<<<2560, 256, 0, stream>>>(weight, w16, 655360);    // 5242880/8
    prep_k<<<4096, 256, 0, stream>>>(poses,  x16, 1048576);   // 8388608/8

    pass_k<0><<<512, 512, 0, stream>>>(x16, w16, bias, nullptr, nullptr, s0);
    pass_k<1><<<512, 512, 0, stream>>>(x16, w16, bias, s0, nullptr, s1);
    pass_k<2><<<512, 512, 0, stream>>>(x16, w16, bias, s0, s1, s2);
    epi_k<<<10, 256, 0, stream>>>(s2, bias, out);
}